// Round 11
// baseline (440.229 us; speedup 1.0000x reference)
//
#include <hip/hip_runtime.h>
#include <float.h>
#include <math.h>

#define ZM 8192
#define CN 16384
#define KD 256
#define HWN 1024
#define ZSTRIDE 262144
#define NCHA 16     // 1024 codes per chunk, running top-2 per chunk

typedef short  s16x8  __attribute__((ext_vector_type(8)));
typedef float  f32x4  __attribute__((ext_vector_type(4)));

// ---------------- norms ----------------

__global__ void norm_z_kernel(const float* __restrict__ z, float* __restrict__ zrinv) {
    __shared__ float sm[4];
    int row = blockIdx.x;
    int b = row >> 10, hw = row & (HWN - 1);
    float v = z[(size_t)b * ZSTRIDE + (size_t)threadIdx.x * HWN + hw];
    float s = v * v;
    #pragma unroll
    for (int m = 32; m; m >>= 1) s += __shfl_xor(s, m, 64);
    if ((threadIdx.x & 63) == 0) sm[threadIdx.x >> 6] = s;
    __syncthreads();
    if (threadIdx.x == 0) {
        float t = sm[0] + sm[1] + sm[2] + sm[3];
        zrinv[row] = 1.0f / fmaxf(sqrtf(t), 1e-12f);
    }
}

__global__ void norm_cb_kernel(const float* __restrict__ cb,
                               float* __restrict__ cbrinv, float* __restrict__ cbsq) {
    __shared__ float sm[4];
    int n = blockIdx.x;
    float v = cb[(size_t)n * KD + threadIdx.x];
    float s = v * v;
    #pragma unroll
    for (int m = 32; m; m >>= 1) s += __shfl_xor(s, m, 64);
    if ((threadIdx.x & 63) == 0) sm[threadIdx.x >> 6] = s;
    __syncthreads();
    if (threadIdx.x == 0) {
        float t = sm[0] + sm[1] + sm[2] + sm[3];
        float r = 1.0f / fmaxf(sqrtf(t), 1e-12f);
        cbrinv[n] = r;
        cbsq[n] = t * r * r;
    }
}

// ---------------- bf16 prep ----------------

__global__ void prep_a_kernel(const float* __restrict__ z, __bf16* __restrict__ Ah) {
    __shared__ float tile[64][65];
    int hw0 = blockIdx.x * 64, c0 = blockIdx.y * 64, b = blockIdx.z;
    int tid = threadIdx.x;
    #pragma unroll
    for (int i = 0; i < 16; ++i) {
        int lin = i * 256 + tid;
        int cl = lin >> 6, hwl = lin & 63;
        tile[cl][hwl] = z[(size_t)b * ZSTRIDE + (size_t)(c0 + cl) * HWN + hw0 + hwl];
    }
    __syncthreads();
    #pragma unroll
    for (int i = 0; i < 16; ++i) {
        int lin = i * 256 + tid;
        int hwl = lin >> 6, cl = lin & 63;
        Ah[(size_t)(b * 1024 + hw0 + hwl) * KD + c0 + cl] = (__bf16)tile[cl][hwl];
    }
}

__global__ void prep_b_kernel(const float* __restrict__ cb, const float* __restrict__ cbrinv,
                              __bf16* __restrict__ Bh) {
    int e4 = blockIdx.x * 256 + threadIdx.x;
    float4 v = ((const float4*)cb)[e4];
    int n = e4 >> 6;
    float sc = cbrinv[n];
    __bf16* ph = &Bh[(size_t)e4 * 4];
    ph[0] = (__bf16)(v.x * sc);
    ph[1] = (__bf16)(v.y * sc);
    ph[2] = (__bf16)(v.z * sc);
    ph[3] = (__bf16)(v.w * sc);
}

// ---------------- bf16 MFMA GEMM + packed-key running top2 ----------------
// BK=64, double-buffered LDS (single barrier/step), depth-2 reg prefetch
// (named rgE/rgO sets — static indexing). 32 steps; step s: t = s>>2,
// k0 = (s&3)*64. Accumulation k-order identical to R10 (bit-identical result).

#define LOADSET(rg, s) do {                                                              \
    const __bf16* pa_ = A + (size_t)(m0 + sr) * KD + (((s) & 3) * 64 + kc);              \
    const __bf16* pb_ = B + (size_t)(chunk * 1024 + ((s) >> 2) * 128 + sr) * KD          \
                          + (((s) & 3) * 64 + kc);                                       \
    rg[0] = *(const uint4*)(pa_);      rg[1] = *(const uint4*)(pa_ + 8);                 \
    rg[2] = *(const uint4*)(pa_ + 16); rg[3] = *(const uint4*)(pa_ + 24);                \
    rg[4] = *(const uint4*)(pb_);      rg[5] = *(const uint4*)(pb_ + 8);                 \
    rg[6] = *(const uint4*)(pb_ + 16); rg[7] = *(const uint4*)(pb_ + 24);                \
} while (0)

#define WRITESET(buf, rg) do {                                                           \
    *(uint4*)&sA[buf][sr][kc +  0] = rg[0];                                              \
    *(uint4*)&sA[buf][sr][kc +  8] = rg[1];                                              \
    *(uint4*)&sA[buf][sr][kc + 16] = rg[2];                                              \
    *(uint4*)&sA[buf][sr][kc + 24] = rg[3];                                              \
    *(uint4*)&sB[buf][sr][kc +  0] = rg[4];                                              \
    *(uint4*)&sB[buf][sr][kc +  8] = rg[5];                                              \
    *(uint4*)&sB[buf][sr][kc + 16] = rg[6];                                              \
    *(uint4*)&sB[buf][sr][kc + 24] = rg[7];                                              \
} while (0)

#define COMPUTE(buf) do {                                                                \
    _Pragma("unroll")                                                                    \
    for (int kh = 0; kh < 64; kh += 32) {                                                \
        s16x8 b0_ = *(const s16x8*)&sB[buf][wn +  0 + fr][kh + fk];                      \
        s16x8 b1_ = *(const s16x8*)&sB[buf][wn + 16 + fr][kh + fk];                      \
        s16x8 b2_ = *(const s16x8*)&sB[buf][wn + 32 + fr][kh + fk];                      \
        s16x8 b3_ = *(const s16x8*)&sB[buf][wn + 48 + fr][kh + fk];                      \
        _Pragma("unroll")                                                                \
        for (int ti = 0; ti < 4; ++ti) {                                                 \
            s16x8 a_ = *(const s16x8*)&sA[buf][wm + ti * 16 + fr][kh + fk];              \
            acc[ti][0] = __builtin_amdgcn_mfma_f32_16x16x32_bf16(a_, b0_, acc[ti][0], 0, 0, 0); \
            acc[ti][1] = __builtin_amdgcn_mfma_f32_16x16x32_bf16(a_, b1_, acc[ti][1], 0, 0, 0); \
            acc[ti][2] = __builtin_amdgcn_mfma_f32_16x16x32_bf16(a_, b2_, acc[ti][2], 0, 0, 0); \
            acc[ti][3] = __builtin_amdgcn_mfma_f32_16x16x32_bf16(a_, b3_, acc[ti][3], 0, 0, 0); \
        }                                                                                \
    }                                                                                    \
} while (0)

#define FOLD(t) do {                                                                     \
    _Pragma("unroll")                                                                    \
    for (int sx = 0; sx < 16; ++sx) {                                                    \
        const int ti_ = sx >> 2, r_ = sx & 3;                                            \
        _Pragma("unroll")                                                                \
        for (int tj = 0; tj < 4; ++tj) {                                                 \
            unsigned u = __float_as_uint(acc[ti_][tj][r_]);                              \
            u ^= ((unsigned)((int)u >> 31)) | 0x80000000u;                               \
            unsigned key = (u & 0xFFFFFC00u) | (unsigned)((t) * 128 + wn + tj * 16 + fr);\
            unsigned h_ = khi[sx];                                                       \
            unsigned mn_ = min(h_, key);                                                 \
            khi[sx] = max(h_, key);                                                      \
            klo[sx] = max(klo[sx], mn_);                                                 \
            acc[ti_][tj][r_] = 0.f;                                                      \
        }                                                                                \
    }                                                                                    \
} while (0)

__global__ __launch_bounds__(256, 2) void gemm_top2_kernel(
    const __bf16* __restrict__ A, const __bf16* __restrict__ B,
    uint2* __restrict__ part)
{
    __shared__ __bf16 sA[2][128][72];   // 144 B rows (16B-aligned), dbuf
    __shared__ __bf16 sB[2][128][72];
    __shared__ uint2 sred[2][128];

    const int tid = threadIdx.x;
    const int l = tid & 63, wid = tid >> 6;
    const int wm = (wid >> 1) * 64, wn = (wid & 1) * 64;
    const int m0 = blockIdx.x * 128;
    const int chunk = blockIdx.y;
    const int fr = l & 15, fk = (l >> 4) * 8;
    const int sr = tid >> 1;            // staged row 0..127
    const int kc = (tid & 1) * 32;      // k offset within 64 (bf16 elems)

    f32x4 acc[4][4];
    #pragma unroll
    for (int ti = 0; ti < 4; ++ti)
        #pragma unroll
        for (int tj = 0; tj < 4; ++tj) acc[ti][tj] = (f32x4){0.f, 0.f, 0.f, 0.f};

    unsigned khi[16], klo[16];
    #pragma unroll
    for (int sx = 0; sx < 16; ++sx) { khi[sx] = 0u; klo[sx] = 0u; }

    uint4 rgE[8], rgO[8];

    // prologue: buf0 <- step0; rgE <- step1; rgO <- step2
    LOADSET(rgE, 0);
    WRITESET(0, rgE);
    LOADSET(rgE, 1);
    LOADSET(rgO, 2);
    __syncthreads();

    for (int sp = 0; sp < 32; sp += 2) {
        // even step sp: read buf0; write step sp+1 (rgE) to buf1; issue sp+3
        COMPUTE(0);
        WRITESET(1, rgE);
        if (sp + 3 < 32) LOADSET(rgE, sp + 3);
        __syncthreads();

        // odd step sp+1: read buf1; write step sp+2 (rgO) to buf0; issue sp+4
        COMPUTE(1);
        if (sp + 2 < 32) WRITESET(0, rgO);
        if (sp + 4 < 32) LOADSET(rgO, sp + 4);
        if ((sp & 3) == 2) FOLD((sp + 1) >> 2);   // s=3,7,..,31 -> t=0..7
        __syncthreads();
    }

    // once per chunk: 16-lane butterfly merge of (hi,lo) key pairs
    #pragma unroll
    for (int sx = 0; sx < 16; ++sx) {
        unsigned h = khi[sx], lo_ = klo[sx];
        #pragma unroll
        for (int m = 1; m < 16; m <<= 1) {
            unsigned oh = (unsigned)__shfl_xor((int)h, m, 64);
            unsigned ol = (unsigned)__shfl_xor((int)lo_, m, 64);
            unsigned nh = max(h, oh);
            lo_ = max(min(h, oh), max(lo_, ol));
            h = nh;
        }
        if ((l & 15) == 0) {
            int rowlb = wm + (sx >> 2) * 16 + (l >> 4) * 4 + (sx & 3);
            sred[wn >> 6][rowlb] = make_uint2(h, lo_);
        }
    }
    __syncthreads();
    if (tid < 128) {
        uint2 pa = sred[0][tid], pb = sred[1][tid];
        unsigned h = max(pa.x, pb.x);
        unsigned lo_ = max(min(pa.x, pb.x), max(pa.y, pb.y));
        part[(size_t)(m0 + tid) * NCHA + chunk] = make_uint2(h, lo_);
    }
}

// ---------------- exact fp32 rescue over all 32 candidates/row ----------------
// Arithmetic bit-identical to the R1 full-scan kernel that matched numpy exactly.

__global__ void rescue_all_kernel(const float* __restrict__ z, const float* __restrict__ cb,
                                  const float* __restrict__ zrinv, const float* __restrict__ cbrinv,
                                  const float* __restrict__ cbsq, const uint2* __restrict__ part,
                                  int* __restrict__ ridx, float* __restrict__ out_idx) {
    int row = blockIdx.x;
    __shared__ float zrow[KD];
    int tid = threadIdx.x;   // 64 threads; lanes 32..63 duplicate slots 0..31
    int b = row >> 10, hw = row & (HWN - 1);
    for (int c = tid; c < KD; c += 64)
        zrow[c] = z[(size_t)b * ZSTRIDE + (size_t)c * HWN + hw];
    __syncthreads();
    int slot = tid & 31;
    uint2 p = part[(size_t)row * NCHA + (slot >> 1)];
    unsigned key = (slot & 1) ? p.y : p.x;
    int n = (slot >> 1) * 1024 + (int)(key & 1023u);
    float sc = cbrinv[n];
    const float4* c4 = (const float4*)(cb + (size_t)n * KD);
    const float4* z4 = (const float4*)zrow;
    float acc = 0.f;
    #pragma unroll 8
    for (int k = 0; k < KD / 4; ++k) {
        float4 cv = c4[k];
        float4 zv = z4[k];
        acc = fmaf(zv.x, cv.x * sc, acc);
        acc = fmaf(zv.y, cv.y * sc, acc);
        acc = fmaf(zv.z, cv.z * sc, acc);
        acc = fmaf(zv.w, cv.w * sc, acc);
    }
    float s = fmaf(zrinv[row], acc, -0.5f * cbsq[n]);
    #pragma unroll
    for (int m = 1; m < 32; m <<= 1) {
        float ov = __shfl_xor(s, m, 64); int on = __shfl_xor(n, m, 64);
        if (ov > s || (ov == s && on < n)) { s = ov; n = on; }
    }
    if (tid == 0) { ridx[row] = n; out_idx[row] = (float)n; }
}

// ---------------- gather + loss ----------------

__global__ void finalize_kernel(const float* __restrict__ z, const float* __restrict__ cb,
                                const int* __restrict__ rows_idx,
                                float* __restrict__ zq_out, float* __restrict__ lpart) {
    __shared__ float sm[4];
    int row = blockIdx.x;
    int b = row >> 10, hw = row & (HWN - 1);
    int c = threadIdx.x;
    int idx = rows_idx[row];
    float zq = cb[(size_t)idx * KD + c];
    size_t zo = (size_t)b * ZSTRIDE + (size_t)c * HWN + hw;
    float zt = z[zo];
    float d = zq - zt;
    zq_out[zo] = zt + d;
    float s = d * d;
    #pragma unroll
    for (int m = 32; m; m >>= 1) s += __shfl_xor(s, m, 64);
    if ((threadIdx.x & 63) == 0) sm[threadIdx.x >> 6] = s;
    __syncthreads();
    if (threadIdx.x == 0) lpart[row] = sm[0] + sm[1] + sm[2] + sm[3];
}

__global__ void loss_final_kernel(const float* __restrict__ lpart, float* __restrict__ out) {
    __shared__ float sm[4];
    float s = 0.0f;
    for (int i = threadIdx.x; i < ZM; i += 256) s += lpart[i];
    #pragma unroll
    for (int m = 32; m; m >>= 1) s += __shfl_xor(s, m, 64);
    if ((threadIdx.x & 63) == 0) sm[threadIdx.x >> 6] = s;
    __syncthreads();
    if (threadIdx.x == 0) {
        float total = sm[0] + sm[1] + sm[2] + sm[3];
        float m = total * (1.0f / 2097152.0f);
        out[0] = fmaf(0.25f, m, m);
    }
}

// ---------------- launch ----------------

extern "C" void kernel_launch(void* const* d_in, const int* in_sizes, int n_in,
                              void* d_out, int out_size, void* d_ws, size_t ws_size,
                              hipStream_t stream) {
    const float* z  = (const float*)d_in[0];
    const float* cb = (const float*)d_in[1];
    float* out = (float*)d_out;

    float* ws = (float*)d_ws;
    float*  zrinv  = ws;                                 // 8192
    float*  cbrinv = zrinv + ZM;                         // 16384
    float*  cbsq   = cbrinv + CN;                        // 16384
    int*    ridx   = (int*)(cbsq + CN);                  // 8192
    float*  lpart  = (float*)(ridx + ZM);                // 8192  (total 57344 floats)
    uint2*  part   = (uint2*)(lpart + ZM);               // 8192*16 uint2 = 1 MB
    __bf16* Ah     = (__bf16*)(part + (size_t)ZM * NCHA);// 4 MB
    __bf16* Bh     = Ah + (size_t)ZM * KD;               // 8 MB  (total ~13.2 MB)

    float* out_loss = out;
    float* out_zq   = out + 1;
    float* out_idx  = out + 1 + (size_t)ZM * KD;

    norm_z_kernel<<<ZM, 256, 0, stream>>>(z, zrinv);
    norm_cb_kernel<<<CN, 256, 0, stream>>>(cb, cbrinv, cbsq);
    prep_a_kernel<<<dim3(16, 4, 8), 256, 0, stream>>>(z, Ah);
    prep_b_kernel<<<CN * KD / 1024, 256, 0, stream>>>(cb, cbrinv, Bh);
    gemm_top2_kernel<<<dim3(ZM / 128, NCHA), 256, 0, stream>>>(Ah, Bh, part);
    rescue_all_kernel<<<ZM, 64, 0, stream>>>(z, cb, zrinv, cbrinv, cbsq, part, ridx, out_idx);
    finalize_kernel<<<ZM, 256, 0, stream>>>(z, cb, ridx, out_zq, lpart);
    loss_final_kernel<<<1, 256, 0, stream>>>(lpart, out_loss);
}

// Round 12
// 199.539 us; speedup vs baseline: 2.2062x; 2.2062x over previous
//
#include <hip/hip_runtime.h>
#include <float.h>
#include <math.h>

#define ZM 8192
#define CN 16384
#define KD 256
#define HWN 1024
#define ZSTRIDE 262144
#define NCHA 16     // 1024 codes per chunk, running top-2 per chunk

typedef short  s16x8  __attribute__((ext_vector_type(8)));
typedef float  f32x4  __attribute__((ext_vector_type(4)));

__device__ inline void gld_lds16(const void* g, void* l) {
    __builtin_amdgcn_global_load_lds((__attribute__((address_space(1))) void*)(g),
                                     (__attribute__((address_space(3))) void*)(l), 16, 0, 0);
}

// ---------------- norm_z: coalesced LDS-transpose, bit-exact tree ----------------
// Preserves R1's exact reduction: per-64-lane-group butterfly sums in c-order,
// then ((T0+T1)+T2)+T3 — identical values, identical op order.

__global__ void norm_z_kernel(const float* __restrict__ z, float* __restrict__ zrinv) {
    __shared__ float tile[256][69];
    int b = blockIdx.x, hw0 = blockIdx.y * 64, tid = threadIdx.x;
    #pragma unroll
    for (int i = 0; i < 16; ++i) {
        int idx4 = i * 256 + tid;             // 4096 float4s = 256c x 16
        int c = idx4 >> 4, h4 = idx4 & 15;
        float4 v = *(const float4*)&z[(size_t)b * ZSTRIDE + (size_t)c * HWN + hw0 + h4 * 4];
        tile[c][h4 * 4 + 0] = v.x;
        tile[c][h4 * 4 + 1] = v.y;
        tile[c][h4 * 4 + 2] = v.z;
        tile[c][h4 * 4 + 3] = v.w;
    }
    __syncthreads();
    int w = tid >> 6, l = tid & 63;
    for (int j = 0; j < 16; ++j) {
        int hwl = w * 16 + j;
        float t_ = 0.f;
        #pragma unroll
        for (int g = 0; g < 4; ++g) {
            float v = tile[g * 64 + l][hwl];
            float s = v * v;
            #pragma unroll
            for (int m = 32; m; m >>= 1) s += __shfl_xor(s, m, 64);
            t_ += s;
        }
        if (l == 0) zrinv[b * 1024 + hw0 + hwl] = 1.0f / fmaxf(sqrtf(t_), 1e-12f);
    }
}

// ---------------- fused cb stats + bf16 prep (one cb read) ----------------

__global__ void cbprep_kernel(const float* __restrict__ cb, float* __restrict__ cbrinv,
                              float* __restrict__ cbsq, __bf16* __restrict__ Bh) {
    __shared__ float sm[4];
    __shared__ float rsh;
    int n = blockIdx.x;
    float v = cb[(size_t)n * KD + threadIdx.x];
    float s = v * v;
    #pragma unroll
    for (int m = 32; m; m >>= 1) s += __shfl_xor(s, m, 64);
    if ((threadIdx.x & 63) == 0) sm[threadIdx.x >> 6] = s;
    __syncthreads();
    if (threadIdx.x == 0) {
        float t = sm[0] + sm[1] + sm[2] + sm[3];
        float r = 1.0f / fmaxf(sqrtf(t), 1e-12f);
        cbrinv[n] = r;
        cbsq[n] = t * r * r;
        rsh = r;
    }
    __syncthreads();
    Bh[(size_t)n * KD + threadIdx.x] = (__bf16)(v * rsh);
}

// ---------------- z transpose: bf16 Ah + f32 Zt (for rescue/finalize) ----------------

__global__ void prep_a_kernel(const float* __restrict__ z, __bf16* __restrict__ Ah,
                              float* __restrict__ Zt) {
    __shared__ float tile[64][65];
    int hw0 = blockIdx.x * 64, c0 = blockIdx.y * 64, b = blockIdx.z;
    int tid = threadIdx.x;
    #pragma unroll
    for (int i = 0; i < 16; ++i) {
        int lin = i * 256 + tid;
        int cl = lin >> 6, hwl = lin & 63;
        tile[cl][hwl] = z[(size_t)b * ZSTRIDE + (size_t)(c0 + cl) * HWN + hw0 + hwl];
    }
    __syncthreads();
    #pragma unroll
    for (int i = 0; i < 16; ++i) {
        int lin = i * 256 + tid;
        int hwl = lin >> 6, cl = lin & 63;
        float v = tile[cl][hwl];
        size_t o = (size_t)(b * 1024 + hw0 + hwl) * KD + c0 + cl;
        Ah[o] = (__bf16)v;
        Zt[o] = v;
    }
}

// ---------------- bf16 MFMA GEMM (global_load_lds, m97-style) + packed-key top2 ----
// BK=32, single LDS buffer, 2 barriers/step (R3-staging, compute-validated).
// Candidate ranking via order-preserving packed keys (R10-validated).

__global__ __launch_bounds__(256, 2) void gemm_top2_kernel(
    const __bf16* __restrict__ A, const __bf16* __restrict__ B,
    uint2* __restrict__ part)
{
    __shared__ __bf16 sA[128][32];
    __shared__ __bf16 sB[128][32];
    __shared__ uint2 sred[2][128];

    const int tid = threadIdx.x;
    const int l = tid & 63;
    const int wid = tid >> 6;
    const int wm = (wid >> 1) * 64, wn = (wid & 1) * 64;
    const int m0 = blockIdx.x * 128;
    const int chunk = blockIdx.y;
    const int fr = l & 15, fk = (l >> 4) * 8;
    const int sr = tid >> 2;            // lane-linear dest: plane byte off = tid*16
    const int kc = (tid & 3) * 8;

    unsigned khi[16], klo[16];
    #pragma unroll
    for (int sx = 0; sx < 16; ++sx) { khi[sx] = 0u; klo[sx] = 0u; }

    for (int t = 0; t < 8; ++t) {
        const int n0 = chunk * 1024 + t * 128;
        f32x4 acc[4][4];
        #pragma unroll
        for (int ti = 0; ti < 4; ++ti)
            #pragma unroll
            for (int tj = 0; tj < 4; ++tj) acc[ti][tj] = (f32x4){0.f, 0.f, 0.f, 0.f};

        for (int g = 0; g < 8; ++g) {
            const int k0 = g * 32;
            #pragma unroll
            for (int s2 = 0; s2 < 2; ++s2) {
                int r = s2 * 64 + sr;
                gld_lds16(&A[(size_t)(m0 + r) * KD + k0 + kc], &sA[r][kc]);
                gld_lds16(&B[(size_t)(n0 + r) * KD + k0 + kc], &sB[r][kc]);
            }
            __syncthreads();   // drains gld_lds (vmcnt) + all waves arrived

            s16x8 bhf[4];
            #pragma unroll
            for (int tj = 0; tj < 4; ++tj)
                bhf[tj] = *(const s16x8*)&sB[wn + tj * 16 + fr][fk];
            #pragma unroll
            for (int ti = 0; ti < 4; ++ti) {
                s16x8 ahf = *(const s16x8*)&sA[wm + ti * 16 + fr][fk];
                #pragma unroll
                for (int tj = 0; tj < 4; ++tj)
                    acc[ti][tj] = __builtin_amdgcn_mfma_f32_16x16x32_bf16(ahf, bhf[tj], acc[ti][tj], 0, 0, 0);
            }
            __syncthreads();   // reads done before next step's staging
        }

        // fold 4 candidates/row into packed running top-2 (pure min/max)
        #pragma unroll
        for (int sx = 0; sx < 16; ++sx) {
            const int ti = sx >> 2, r = sx & 3;
            #pragma unroll
            for (int tj = 0; tj < 4; ++tj) {
                unsigned u = __float_as_uint(acc[ti][tj][r]);
                u ^= ((unsigned)((int)u >> 31)) | 0x80000000u;
                unsigned key = (u & 0xFFFFFC00u) | (unsigned)(t * 128 + wn + tj * 16 + fr);
                unsigned h = khi[sx];
                unsigned mn = min(h, key);
                khi[sx] = max(h, key);
                klo[sx] = max(klo[sx], mn);
            }
        }
    }

    // 16-lane butterfly merge, then cross-wave merge via LDS
    #pragma unroll
    for (int sx = 0; sx < 16; ++sx) {
        unsigned h = khi[sx], lo_ = klo[sx];
        #pragma unroll
        for (int m = 1; m < 16; m <<= 1) {
            unsigned oh = (unsigned)__shfl_xor((int)h, m, 64);
            unsigned ol = (unsigned)__shfl_xor((int)lo_, m, 64);
            unsigned nh = max(h, oh);
            lo_ = max(min(h, oh), max(lo_, ol));
            h = nh;
        }
        if ((l & 15) == 0) {
            int rowlb = wm + (sx >> 2) * 16 + (l >> 4) * 4 + (sx & 3);
            sred[wn >> 6][rowlb] = make_uint2(h, lo_);
        }
    }
    __syncthreads();
    if (tid < 128) {
        uint2 pa = sred[0][tid], pb = sred[1][tid];
        unsigned h = max(pa.x, pb.x);
        unsigned lo_ = max(min(pa.x, pb.x), max(pa.y, pb.y));
        part[(size_t)(m0 + tid) * NCHA + chunk] = make_uint2(h, lo_);
    }
}

// ---------------- exact fp32 rescue over all 32 candidates/row ----------------
// Arithmetic bit-identical to the R1 full-scan kernel; zrow from Zt (same bits).

__global__ void rescue_all_kernel(const float* __restrict__ Zt, const float* __restrict__ cb,
                                  const float* __restrict__ zrinv, const float* __restrict__ cbrinv,
                                  const float* __restrict__ cbsq, const uint2* __restrict__ part,
                                  int* __restrict__ ridx, float* __restrict__ out_idx) {
    int row = blockIdx.x;
    __shared__ float zrow[KD];
    int tid = threadIdx.x;   // 64 threads; lanes 32..63 duplicate slots 0..31
    ((float4*)zrow)[tid] = ((const float4*)(Zt + (size_t)row * KD))[tid];
    __syncthreads();
    int slot = tid & 31;
    uint2 p = part[(size_t)row * NCHA + (slot >> 1)];
    unsigned key = (slot & 1) ? p.y : p.x;
    int n = (slot >> 1) * 1024 + (int)(key & 1023u);
    float sc = cbrinv[n];
    const float4* c4 = (const float4*)(cb + (size_t)n * KD);
    const float4* z4 = (const float4*)zrow;
    float acc = 0.f;
    #pragma unroll 8
    for (int k = 0; k < KD / 4; ++k) {
        float4 cv = c4[k];
        float4 zv = z4[k];
        acc = fmaf(zv.x, cv.x * sc, acc);
        acc = fmaf(zv.y, cv.y * sc, acc);
        acc = fmaf(zv.z, cv.z * sc, acc);
        acc = fmaf(zv.w, cv.w * sc, acc);
    }
    float s = fmaf(zrinv[row], acc, -0.5f * cbsq[n]);
    #pragma unroll
    for (int m = 1; m < 32; m <<= 1) {
        float ov = __shfl_xor(s, m, 64); int on = __shfl_xor(n, m, 64);
        if (ov > s || (ov == s && on < n)) { s = ov; n = on; }
    }
    if (tid == 0) { ridx[row] = n; out_idx[row] = (float)n; }
}

// ---------------- gather + z_q output (coalesced via LDS transpose) + loss ----------

__global__ void finalize_kernel(const float* __restrict__ Zt, const float* __restrict__ cb,
                                const int* __restrict__ ridx,
                                float* __restrict__ zq_out, float* __restrict__ lpart) {
    __shared__ float zqt[64][257];
    __shared__ int idxs[64];
    __shared__ float sm[4];
    int b = blockIdx.x, hw0 = blockIdx.y * 64, tid = threadIdx.x;
    if (tid < 64) idxs[tid] = ridx[b * 1024 + hw0 + tid];
    __syncthreads();
    float dsum = 0.f;
    for (int i = 0; i < 64; ++i) {                 // row i; lanes = channel c
        int row = b * 1024 + hw0 + i;
        float zt = Zt[(size_t)row * KD + tid];
        float zq = cb[(size_t)idxs[i] * KD + tid];
        float d = zq - zt;
        zqt[i][tid] = zt + d;                      // straight-through arithmetic
        dsum = fmaf(d, d, dsum);
    }
    #pragma unroll
    for (int m = 32; m; m >>= 1) dsum += __shfl_xor(dsum, m, 64);
    if ((tid & 63) == 0) sm[tid >> 6] = dsum;
    __syncthreads();
    if (tid == 0) lpart[blockIdx.x * 16 + blockIdx.y] = sm[0] + sm[1] + sm[2] + sm[3];
    // write phase: lanes = hw (coalesced)
    for (int i = 0; i < 64; ++i) {
        int idx = i * 256 + tid;
        int c = idx >> 6, hwl = idx & 63;
        zq_out[(size_t)b * ZSTRIDE + (size_t)c * HWN + hw0 + hwl] = zqt[hwl][c];
    }
}

__global__ void loss_final_kernel(const float* __restrict__ lpart, float* __restrict__ out) {
    __shared__ float sm[4];
    float s = 0.0f;
    for (int i = threadIdx.x; i < 128; i += 256) s += lpart[i];
    #pragma unroll
    for (int m = 32; m; m >>= 1) s += __shfl_xor(s, m, 64);
    if ((threadIdx.x & 63) == 0) sm[threadIdx.x >> 6] = s;
    __syncthreads();
    if (threadIdx.x == 0) {
        float total = sm[0] + sm[1] + sm[2] + sm[3];
        float m = total * (1.0f / 2097152.0f);
        out[0] = fmaf(0.25f, m, m);
    }
}

// ---------------- launch ----------------

extern "C" void kernel_launch(void* const* d_in, const int* in_sizes, int n_in,
                              void* d_out, int out_size, void* d_ws, size_t ws_size,
                              hipStream_t stream) {
    const float* z  = (const float*)d_in[0];
    const float* cb = (const float*)d_in[1];
    float* out = (float*)d_out;

    float* ws = (float*)d_ws;
    float*  zrinv  = ws;                                 // 8192
    float*  cbrinv = zrinv + ZM;                         // 16384
    float*  cbsq   = cbrinv + CN;                        // 16384
    int*    ridx   = (int*)(cbsq + CN);                  // 8192
    float*  lpart  = (float*)(ridx + ZM);                // 8192 (128 used)  -> 57344 floats
    uint2*  part   = (uint2*)(lpart + ZM);               // 1 MB
    __bf16* Ah     = (__bf16*)(part + (size_t)ZM * NCHA);// 4 MB
    __bf16* Bh     = Ah + (size_t)ZM * KD;               // 8 MB
    float*  Zt     = (float*)(Bh + (size_t)CN * KD);     // 8 MB  (total ~21.5 MB)

    float* out_loss = out;
    float* out_zq   = out + 1;
    float* out_idx  = out + 1 + (size_t)ZM * KD;

    norm_z_kernel<<<dim3(8, 16), 256, 0, stream>>>(z, zrinv);
    cbprep_kernel<<<CN, 256, 0, stream>>>(cb, cbrinv, cbsq, Bh);
    prep_a_kernel<<<dim3(16, 4, 8), 256, 0, stream>>>(z, Ah, Zt);
    gemm_top2_kernel<<<dim3(ZM / 128, NCHA), 256, 0, stream>>>(Ah, Bh, part);
    rescue_all_kernel<<<ZM, 64, 0, stream>>>(Zt, cb, zrinv, cbrinv, cbsq, part, ridx, out_idx);
    finalize_kernel<<<dim3(8, 16), 256, 0, stream>>>(Zt, cb, ridx, out_zq, lpart);
    loss_final_kernel<<<1, 256, 0, stream>>>(lpart, out_loss);
}

// Round 15
// 198.791 us; speedup vs baseline: 2.2145x; 1.0038x over previous
//
#include <hip/hip_runtime.h>
#include <float.h>
#include <math.h>

#define ZM 8192
#define CN 16384
#define KD 256
#define HWN 1024
#define ZSTRIDE 262144
#define NCHA 16     // 1024 codes per chunk, running top-2 per chunk

typedef short  s16x8  __attribute__((ext_vector_type(8)));
typedef float  f32x4  __attribute__((ext_vector_type(4)));

__device__ inline void gld_lds16(const void* g, void* l) {
    __builtin_amdgcn_global_load_lds((__attribute__((address_space(1))) void*)(g),
                                     (__attribute__((address_space(3))) void*)(l), 16, 0, 0);
}

// ---------------- fused cb stats + bf16 prep (one cb read) ----------------

__global__ void cbprep_kernel(const float* __restrict__ cb, float* __restrict__ cbrinv,
                              float* __restrict__ cbsq, __bf16* __restrict__ Bh) {
    __shared__ float sm[4];
    __shared__ float rsh;
    int n = blockIdx.x;
    float v = cb[(size_t)n * KD + threadIdx.x];
    float s = v * v;
    #pragma unroll
    for (int m = 32; m; m >>= 1) s += __shfl_xor(s, m, 64);
    if ((threadIdx.x & 63) == 0) sm[threadIdx.x >> 6] = s;
    __syncthreads();
    if (threadIdx.x == 0) {
        float t = sm[0] + sm[1] + sm[2] + sm[3];
        float r = 1.0f / fmaxf(sqrtf(t), 1e-12f);
        cbrinv[n] = r;
        cbsq[n] = t * r * r;
        rsh = r;
    }
    __syncthreads();
    Bh[(size_t)n * KD + threadIdx.x] = (__bf16)(v * rsh);
}

// ---------------- z transpose: bf16 Ah + f32 Zt ----------------

__global__ void prep_a_kernel(const float* __restrict__ z, __bf16* __restrict__ Ah,
                              float* __restrict__ Zt) {
    __shared__ float tile[64][65];
    int hw0 = blockIdx.x * 64, c0 = blockIdx.y * 64, b = blockIdx.z;
    int tid = threadIdx.x;
    #pragma unroll
    for (int i = 0; i < 16; ++i) {
        int lin = i * 256 + tid;
        int cl = lin >> 6, hwl = lin & 63;
        tile[cl][hwl] = z[(size_t)b * ZSTRIDE + (size_t)(c0 + cl) * HWN + hw0 + hwl];
    }
    __syncthreads();
    #pragma unroll
    for (int i = 0; i < 16; ++i) {
        int lin = i * 256 + tid;
        int hwl = lin >> 6, cl = lin & 63;
        float v = tile[cl][hwl];
        size_t o = (size_t)(b * 1024 + hw0 + hwl) * KD + c0 + cl;
        Ah[o] = (__bf16)v;
        Zt[o] = v;
    }
}

// ---------------- bf16 MFMA GEMM: 2-phase pipelined gld_lds + packed-key top2 ----
// T3 minimum-2-phase: STAGE(buf^1, s+1) issued BEFORE COMPUTE(buf); the single
// __syncthreads() per step (compiler emits vmcnt(0) drain before s_barrier)
// guarantees staged data visible and prior reads done. T1 XCD swizzle: each
// XCD owns 2 chunks so its B-panel (1 MB) stays in its private L2.

__global__ __launch_bounds__(256, 2) void gemm_top2_kernel(
    const __bf16* __restrict__ A, const __bf16* __restrict__ B,
    uint2* __restrict__ part)
{
    __shared__ __bf16 sA[2][128][32];
    __shared__ __bf16 sB[2][128][32];
    __shared__ uint2 sred[2][128];

    const int tid = threadIdx.x;
    const int l = tid & 63;
    const int wid = tid >> 6;
    const int wm = (wid >> 1) * 64, wn = (wid & 1) * 64;

    // XCD-aware remap (bijective: 1024 blocks, 8 XCDs)
    const int bid = blockIdx.x;
    const int wl = (bid & 7) * 128 + (bid >> 3);
    const int chunk = wl >> 6;            // 0..15
    const int m0 = (wl & 63) * 128;

    const int fr = l & 15, fk = (l >> 4) * 8;
    const int sr = tid >> 2;              // lane-linear dest: byte off = tid*16
    const int kc = (tid & 3) * 8;

    unsigned khi[16], klo[16];
    #pragma unroll
    for (int sx = 0; sx < 16; ++sx) { khi[sx] = 0u; klo[sx] = 0u; }

    auto stage = [&](int buf, int s) {
        const int t = s >> 3, k0 = (s & 7) * 32;
        const int n0 = chunk * 1024 + t * 128;
        #pragma unroll
        for (int s2 = 0; s2 < 2; ++s2) {
            int r = s2 * 64 + sr;
            gld_lds16(&A[(size_t)(m0 + r) * KD + k0 + kc], &sA[buf][r][kc]);
            gld_lds16(&B[(size_t)(n0 + r) * KD + k0 + kc], &sB[buf][r][kc]);
        }
    };

    f32x4 acc[4][4];
    #pragma unroll
    for (int ti = 0; ti < 4; ++ti)
        #pragma unroll
        for (int tj = 0; tj < 4; ++tj) acc[ti][tj] = (f32x4){0.f, 0.f, 0.f, 0.f};

    stage(0, 0);
    __syncthreads();                       // prologue stage landed

    int cur = 0;
    for (int s = 0; s < 64; ++s) {
        if (s + 1 < 64) stage(cur ^ 1, s + 1);   // loads fly during compute

        s16x8 bhf[4];
        #pragma unroll
        for (int tj = 0; tj < 4; ++tj)
            bhf[tj] = *(const s16x8*)&sB[cur][wn + tj * 16 + fr][fk];
        #pragma unroll
        for (int ti = 0; ti < 4; ++ti) {
            s16x8 ahf = *(const s16x8*)&sA[cur][wm + ti * 16 + fr][fk];
            #pragma unroll
            for (int tj = 0; tj < 4; ++tj)
                acc[ti][tj] = __builtin_amdgcn_mfma_f32_16x16x32_bf16(ahf, bhf[tj], acc[ti][tj], 0, 0, 0);
        }

        if ((s & 7) == 7) {
            const int t = s >> 3;
            // fold 4 candidates/row into packed running top-2, zero acc
            #pragma unroll
            for (int sx = 0; sx < 16; ++sx) {
                const int ti = sx >> 2, r = sx & 3;
                #pragma unroll
                for (int tj = 0; tj < 4; ++tj) {
                    unsigned u = __float_as_uint(acc[ti][tj][r]);
                    u ^= ((unsigned)((int)u >> 31)) | 0x80000000u;
                    unsigned key = (u & 0xFFFFFC00u) | (unsigned)(t * 128 + wn + tj * 16 + fr);
                    unsigned h = khi[sx];
                    unsigned mn = min(h, key);
                    khi[sx] = max(h, key);
                    klo[sx] = max(klo[sx], mn);
                    acc[ti][tj][r] = 0.f;
                }
            }
        }
        __syncthreads();                   // vmcnt(0) drain + barrier
        cur ^= 1;
    }

    // 16-lane butterfly merge, then cross-wave merge via LDS
    #pragma unroll
    for (int sx = 0; sx < 16; ++sx) {
        unsigned h = khi[sx], lo_ = klo[sx];
        #pragma unroll
        for (int m = 1; m < 16; m <<= 1) {
            unsigned oh = (unsigned)__shfl_xor((int)h, m, 64);
            unsigned ol = (unsigned)__shfl_xor((int)lo_, m, 64);
            unsigned nh = max(h, oh);
            lo_ = max(min(h, oh), max(lo_, ol));
            h = nh;
        }
        if ((l & 15) == 0) {
            int rowlb = wm + (sx >> 2) * 16 + (l >> 4) * 4 + (sx & 3);
            sred[wn >> 6][rowlb] = make_uint2(h, lo_);
        }
    }
    __syncthreads();
    if (tid < 128) {
        uint2 pa = sred[0][tid], pb = sred[1][tid];
        unsigned h = max(pa.x, pb.x);
        unsigned lo_ = max(min(pa.x, pb.x), max(pa.y, pb.y));
        part[(size_t)(m0 + tid) * NCHA + chunk] = make_uint2(h, lo_);
    }
}

// ---------------- exact fp32 rescue over all 32 candidates/row ----------------
// zrinv recomputed with a bit-identical replication of R1's reduction tree.

__global__ void rescue_all_kernel(const float* __restrict__ Zt, const float* __restrict__ cb,
                                  const float* __restrict__ cbrinv, const float* __restrict__ cbsq,
                                  const uint2* __restrict__ part,
                                  int* __restrict__ ridx, float* __restrict__ out_idx) {
    int row = blockIdx.x;
    __shared__ float zrow[KD];
    int tid = threadIdx.x;   // 64 threads; lanes 32..63 duplicate slots 0..31
    ((float4*)zrow)[tid] = ((const float4*)(Zt + (size_t)row * KD))[tid];
    __syncthreads();

    // zrinv: 4 per-group butterflies (m=32..1), summed in group order — same
    // values, same lanes, same op order as the R1 norm_z kernel (absmax 0.0).
    float tot = 0.f;
    #pragma unroll
    for (int w = 0; w < 4; ++w) {
        float v = zrow[w * 64 + tid];
        float s = v * v;
        #pragma unroll
        for (int m = 32; m; m >>= 1) s += __shfl_xor(s, m, 64);
        tot += s;
    }
    float zrinv = 1.0f / fmaxf(sqrtf(tot), 1e-12f);

    int slot = tid & 31;
    uint2 p = part[(size_t)row * NCHA + (slot >> 1)];
    unsigned key = (slot & 1) ? p.y : p.x;
    int n = (slot >> 1) * 1024 + (int)(key & 1023u);
    float sc = cbrinv[n];
    const float4* c4 = (const float4*)(cb + (size_t)n * KD);
    const float4* z4 = (const float4*)zrow;
    float acc = 0.f;
    #pragma unroll 8
    for (int k = 0; k < KD / 4; ++k) {
        float4 cv = c4[k];
        float4 zv = z4[k];
        acc = fmaf(zv.x, cv.x * sc, acc);
        acc = fmaf(zv.y, cv.y * sc, acc);
        acc = fmaf(zv.z, cv.z * sc, acc);
        acc = fmaf(zv.w, cv.w * sc, acc);
    }
    float s = fmaf(zrinv, acc, -0.5f * cbsq[n]);
    #pragma unroll
    for (int m = 1; m < 32; m <<= 1) {
        float ov = __shfl_xor(s, m, 64); int on = __shfl_xor(n, m, 64);
        if (ov > s || (ov == s && on < n)) { s = ov; n = on; }
    }
    if (tid == 0) { ridx[row] = n; out_idx[row] = (float)n; }
}

// ---------------- gather + z_q output (coalesced via LDS transpose) + loss ----------

__global__ void finalize_kernel(const float* __restrict__ Zt, const float* __restrict__ cb,
                                const int* __restrict__ ridx,
                                float* __restrict__ zq_out, float* __restrict__ lpart) {
    __shared__ float zqt[64][257];
    __shared__ int idxs[64];
    __shared__ float sm[4];
    int b = blockIdx.x, hw0 = blockIdx.y * 64, tid = threadIdx.x;
    if (tid < 64) idxs[tid] = ridx[b * 1024 + hw0 + tid];
    __syncthreads();
    float dsum = 0.f;
    for (int i = 0; i < 64; ++i) {                 // row i; lanes = channel c
        int row = b * 1024 + hw0 + i;
        float zt = Zt[(size_t)row * KD + tid];
        float zq = cb[(size_t)idxs[i] * KD + tid];
        float d = zq - zt;
        zqt[i][tid] = zt + d;                      // straight-through arithmetic
        dsum = fmaf(d, d, dsum);
    }
    #pragma unroll
    for (int m = 32; m; m >>= 1) dsum += __shfl_xor(dsum, m, 64);
    if ((tid & 63) == 0) sm[tid >> 6] = dsum;
    __syncthreads();
    if (tid == 0) lpart[blockIdx.x * 16 + blockIdx.y] = sm[0] + sm[1] + sm[2] + sm[3];
    // write phase: lanes = hw (coalesced)
    for (int i = 0; i < 64; ++i) {
        int idx = i * 256 + tid;
        int c = idx >> 6, hwl = idx & 63;
        zq_out[(size_t)b * ZSTRIDE + (size_t)c * HWN + hw0 + hwl] = zqt[hwl][c];
    }
}

__global__ void loss_final_kernel(const float* __restrict__ lpart, float* __restrict__ out) {
    __shared__ float sm[4];
    float s = 0.0f;
    for (int i = threadIdx.x; i < 128; i += 256) s += lpart[i];
    #pragma unroll
    for (int m = 32; m; m >>= 1) s += __shfl_xor(s, m, 64);
    if ((threadIdx.x & 63) == 0) sm[threadIdx.x >> 6] = s;
    __syncthreads();
    if (threadIdx.x == 0) {
        float total = sm[0] + sm[1] + sm[2] + sm[3];
        float m = total * (1.0f / 2097152.0f);
        out[0] = fmaf(0.25f, m, m);
    }
}

// ---------------- launch ----------------

extern "C" void kernel_launch(void* const* d_in, const int* in_sizes, int n_in,
                              void* d_out, int out_size, void* d_ws, size_t ws_size,
                              hipStream_t stream) {
    const float* z  = (const float*)d_in[0];
    const float* cb = (const float*)d_in[1];
    float* out = (float*)d_out;

    float* ws = (float*)d_ws;
    float*  cbrinv = ws;                                 // 16384
    float*  cbsq   = cbrinv + CN;                        // 16384
    int*    ridx   = (int*)(cbsq + CN);                  // 8192
    float*  lpart  = (float*)(ridx + ZM);                // 8192 (128 used)
    uint2*  part   = (uint2*)(lpart + ZM);               // 1 MB (16B-aligned)
    __bf16* Ah     = (__bf16*)(part + (size_t)ZM * NCHA);// 4 MB
    __bf16* Bh     = Ah + (size_t)ZM * KD;               // 8 MB
    float*  Zt     = (float*)(Bh + (size_t)CN * KD);     // 8 MB  (total ~21.4 MB)

    float* out_loss = out;
    float* out_zq   = out + 1;
    float* out_idx  = out + 1 + (size_t)ZM * KD;

    cbprep_kernel<<<CN, 256, 0, stream>>>(cb, cbrinv, cbsq, Bh);
    prep_a_kernel<<<dim3(16, 4, 8), 256, 0, stream>>>(z, Ah, Zt);
    gemm_top2_kernel<<<1024, 256, 0, stream>>>(Ah, Bh, part);
    rescue_all_kernel<<<ZM, 64, 0, stream>>>(Zt, cb, cbrinv, cbsq, part, ridx, out_idx);
    finalize_kernel<<<dim3(8, 16), 256, 0, stream>>>(Zt, cb, ridx, out_zq, lpart);
    loss_final_kernel<<<1, 256, 0, stream>>>(lpart, out_loss);
}

// Round 16
// 187.842 us; speedup vs baseline: 2.3436x; 1.0583x over previous
//
#include <hip/hip_runtime.h>
#include <float.h>
#include <math.h>

#define ZM 8192
#define CN 16384
#define KD 256
#define HWN 1024
#define ZSTRIDE 262144
#define NCHA 16     // 1024 codes per chunk, running top-2 per chunk

typedef short  s16x8  __attribute__((ext_vector_type(8)));
typedef float  f32x4  __attribute__((ext_vector_type(4)));

__device__ inline void gld_lds16(const void* g, void* l) {
    __builtin_amdgcn_global_load_lds((__attribute__((address_space(1))) void*)(g),
                                     (__attribute__((address_space(3))) void*)(l), 16, 0, 0);
}

// ---------------- fused cb stats + bf16 prep (one cb read) ----------------

__global__ void cbprep_kernel(const float* __restrict__ cb, float* __restrict__ cbrinv,
                              float* __restrict__ cbsq, __bf16* __restrict__ Bh) {
    __shared__ float sm[4];
    __shared__ float rsh;
    int n = blockIdx.x;
    float v = cb[(size_t)n * KD + threadIdx.x];
    float s = v * v;
    #pragma unroll
    for (int m = 32; m; m >>= 1) s += __shfl_xor(s, m, 64);
    if ((threadIdx.x & 63) == 0) sm[threadIdx.x >> 6] = s;
    __syncthreads();
    if (threadIdx.x == 0) {
        float t = sm[0] + sm[1] + sm[2] + sm[3];
        float r = 1.0f / fmaxf(sqrtf(t), 1e-12f);
        cbrinv[n] = r;
        cbsq[n] = t * r * r;
        rsh = r;
    }
    __syncthreads();
    Bh[(size_t)n * KD + threadIdx.x] = (__bf16)(v * rsh);
}

// ---------------- z transpose: bf16 Ah + f32 Zt ----------------

__global__ void prep_a_kernel(const float* __restrict__ z, __bf16* __restrict__ Ah,
                              float* __restrict__ Zt) {
    __shared__ float tile[64][65];
    int hw0 = blockIdx.x * 64, c0 = blockIdx.y * 64, b = blockIdx.z;
    int tid = threadIdx.x;
    #pragma unroll
    for (int i = 0; i < 16; ++i) {
        int lin = i * 256 + tid;
        int cl = lin >> 6, hwl = lin & 63;
        tile[cl][hwl] = z[(size_t)b * ZSTRIDE + (size_t)(c0 + cl) * HWN + hw0 + hwl];
    }
    __syncthreads();
    #pragma unroll
    for (int i = 0; i < 16; ++i) {
        int lin = i * 256 + tid;
        int hwl = lin >> 6, cl = lin & 63;
        float v = tile[cl][hwl];
        size_t o = (size_t)(b * 1024 + hw0 + hwl) * KD + c0 + cl;
        Ah[o] = (__bf16)v;
        Zt[o] = v;
    }
}

// ---------------- bf16 MFMA GEMM: BK=64, XOR-swizzled gld_lds staging ----------
// Rule-#21-compliant swizzle: LDS dest is lane-linear (gld_lds requirement);
// the GLOBAL source granule index is permuted c^(r&7), and ds_read applies the
// same involution — 16-lane frag reads hit all 32 banks at 2 lanes/bank (free).
// 32 steps (BK=64), single barrier per step, 2-phase stage-ahead.
// K accumulation order is bit-identical to the R12 pass.

__global__ __launch_bounds__(256, 2) void gemm_top2_kernel(
    const __bf16* __restrict__ A, const __bf16* __restrict__ B,
    uint2* __restrict__ part)
{
    __shared__ __bf16 sA[2][128 * 64];   // [buf][row*8 + kgranule][8 elems]
    __shared__ __bf16 sB[2][128 * 64];
    __shared__ uint2 sred[2][128];

    const int tid = threadIdx.x;
    const int l = tid & 63;
    const int wid = tid >> 6;
    const int wm = (wid >> 1) * 64, wn = (wid & 1) * 64;
    const int m0 = blockIdx.x * 128;     // linear grid: A-panel/XCD stays L2-resident
    const int chunk = blockIdx.y;
    const int fr = l & 15;
    const int fkg = l >> 4;              // k-granule subindex 0..3

    unsigned khi[16], klo[16];
    #pragma unroll
    for (int sx = 0; sx < 16; ++sx) { khi[sx] = 0u; klo[sx] = 0u; }

    auto stage = [&](int buf, int s) {
        const int t = s >> 2, k0 = (s & 3) * 64;
        const int n0 = chunk * 1024 + t * 128;
        #pragma unroll
        for (int j = 0; j < 4; ++j) {
            int sl = j * 256 + tid;              // 16B slot 0..1023 (wave-contiguous)
            int r = sl >> 3, c = sl & 7;
            int cs = c ^ (r & 7);                // inverse-swizzled global granule
            gld_lds16(&A[(size_t)(m0 + r) * KD + k0 + cs * 8], &sA[buf][sl * 8]);
            gld_lds16(&B[(size_t)(n0 + r) * KD + k0 + cs * 8], &sB[buf][sl * 8]);
        }
    };

    f32x4 acc[4][4];
    #pragma unroll
    for (int ti = 0; ti < 4; ++ti)
        #pragma unroll
        for (int tj = 0; tj < 4; ++tj) acc[ti][tj] = (f32x4){0.f, 0.f, 0.f, 0.f};

    stage(0, 0);
    __syncthreads();                      // prologue stage landed

    int cur = 0;
    for (int s = 0; s < 32; ++s) {
        if (s + 1 < 32) stage(cur ^ 1, s + 1);   // next-step loads fly under compute

        #pragma unroll
        for (int kh = 0; kh < 2; ++kh) {         // k halves: granules 0..3 / 4..7
            s16x8 bhf[4];
            #pragma unroll
            for (int tj = 0; tj < 4; ++tj) {
                int row = wn + tj * 16 + fr;
                int cg = (kh * 4 + fkg) ^ (row & 7);
                bhf[tj] = *(const s16x8*)&sB[cur][row * 64 + cg * 8];
            }
            #pragma unroll
            for (int ti = 0; ti < 4; ++ti) {
                int row = wm + ti * 16 + fr;
                int cg = (kh * 4 + fkg) ^ (row & 7);
                s16x8 ahf = *(const s16x8*)&sA[cur][row * 64 + cg * 8];
                #pragma unroll
                for (int tj = 0; tj < 4; ++tj)
                    acc[ti][tj] = __builtin_amdgcn_mfma_f32_16x16x32_bf16(ahf, bhf[tj], acc[ti][tj], 0, 0, 0);
            }
        }

        if ((s & 3) == 3) {
            const int t = s >> 2;
            // fold 4 candidates/row into packed running top-2, zero acc
            #pragma unroll
            for (int sx = 0; sx < 16; ++sx) {
                const int ti = sx >> 2, r = sx & 3;
                #pragma unroll
                for (int tj = 0; tj < 4; ++tj) {
                    unsigned u = __float_as_uint(acc[ti][tj][r]);
                    u ^= ((unsigned)((int)u >> 31)) | 0x80000000u;
                    unsigned key = (u & 0xFFFFFC00u) | (unsigned)(t * 128 + wn + tj * 16 + fr);
                    unsigned h = khi[sx];
                    unsigned mn = min(h, key);
                    khi[sx] = max(h, key);
                    klo[sx] = max(klo[sx], mn);
                    acc[ti][tj][r] = 0.f;
                }
            }
        }
        __syncthreads();                  // vmcnt(0) drain + barrier
        cur ^= 1;
    }

    // 16-lane butterfly merge, then cross-wave merge via LDS
    #pragma unroll
    for (int sx = 0; sx < 16; ++sx) {
        unsigned h = khi[sx], lo_ = klo[sx];
        #pragma unroll
        for (int m = 1; m < 16; m <<= 1) {
            unsigned oh = (unsigned)__shfl_xor((int)h, m, 64);
            unsigned ol = (unsigned)__shfl_xor((int)lo_, m, 64);
            unsigned nh = max(h, oh);
            lo_ = max(min(h, oh), max(lo_, ol));
            h = nh;
        }
        if ((l & 15) == 0) {
            int rowlb = wm + (sx >> 2) * 16 + (l >> 4) * 4 + (sx & 3);
            sred[wn >> 6][rowlb] = make_uint2(h, lo_);
        }
    }
    __syncthreads();
    if (tid < 128) {
        uint2 pa = sred[0][tid], pb = sred[1][tid];
        unsigned h = max(pa.x, pb.x);
        unsigned lo_ = max(min(pa.x, pb.x), max(pa.y, pb.y));
        part[(size_t)(m0 + tid) * NCHA + chunk] = make_uint2(h, lo_);
    }
}

// ---------------- exact fp32 rescue over all 32 candidates/row ----------------
// zrinv recomputed with a bit-identical replication of R1's reduction tree.

__global__ void rescue_all_kernel(const float* __restrict__ Zt, const float* __restrict__ cb,
                                  const float* __restrict__ cbrinv, const float* __restrict__ cbsq,
                                  const uint2* __restrict__ part,
                                  int* __restrict__ ridx, float* __restrict__ out_idx) {
    int row = blockIdx.x;
    __shared__ float zrow[KD];
    int tid = threadIdx.x;   // 64 threads; lanes 32..63 duplicate slots 0..31
    ((float4*)zrow)[tid] = ((const float4*)(Zt + (size_t)row * KD))[tid];
    __syncthreads();

    float tot = 0.f;
    #pragma unroll
    for (int w = 0; w < 4; ++w) {
        float v = zrow[w * 64 + tid];
        float s = v * v;
        #pragma unroll
        for (int m = 32; m; m >>= 1) s += __shfl_xor(s, m, 64);
        tot += s;
    }
    float zrinv = 1.0f / fmaxf(sqrtf(tot), 1e-12f);

    int slot = tid & 31;
    uint2 p = part[(size_t)row * NCHA + (slot >> 1)];
    unsigned key = (slot & 1) ? p.y : p.x;
    int n = (slot >> 1) * 1024 + (int)(key & 1023u);
    float sc = cbrinv[n];
    const float4* c4 = (const float4*)(cb + (size_t)n * KD);
    const float4* z4 = (const float4*)zrow;
    float acc = 0.f;
    #pragma unroll 8
    for (int k = 0; k < KD / 4; ++k) {
        float4 cv = c4[k];
        float4 zv = z4[k];
        acc = fmaf(zv.x, cv.x * sc, acc);
        acc = fmaf(zv.y, cv.y * sc, acc);
        acc = fmaf(zv.z, cv.z * sc, acc);
        acc = fmaf(zv.w, cv.w * sc, acc);
    }
    float s = fmaf(zrinv, acc, -0.5f * cbsq[n]);
    #pragma unroll
    for (int m = 1; m < 32; m <<= 1) {
        float ov = __shfl_xor(s, m, 64); int on = __shfl_xor(n, m, 64);
        if (ov > s || (ov == s && on < n)) { s = ov; n = on; }
    }
    if (tid == 0) { ridx[row] = n; out_idx[row] = (float)n; }
}

// ---------------- gather + z_q output (coalesced via LDS transpose) + loss ----------

__global__ void finalize_kernel(const float* __restrict__ Zt, const float* __restrict__ cb,
                                const int* __restrict__ ridx,
                                float* __restrict__ zq_out, float* __restrict__ lpart) {
    __shared__ float zqt[64][257];
    __shared__ int idxs[64];
    __shared__ float sm[4];
    int b = blockIdx.x, hw0 = blockIdx.y * 64, tid = threadIdx.x;
    if (tid < 64) idxs[tid] = ridx[b * 1024 + hw0 + tid];
    __syncthreads();
    float dsum = 0.f;
    for (int i = 0; i < 64; ++i) {                 // row i; lanes = channel c
        int row = b * 1024 + hw0 + i;
        float zt = Zt[(size_t)row * KD + tid];
        float zq = cb[(size_t)idxs[i] * KD + tid];
        float d = zq - zt;
        zqt[i][tid] = zt + d;                      // straight-through arithmetic
        dsum = fmaf(d, d, dsum);
    }
    #pragma unroll
    for (int m = 32; m; m >>= 1) dsum += __shfl_xor(dsum, m, 64);
    if ((tid & 63) == 0) sm[tid >> 6] = dsum;
    __syncthreads();
    if (tid == 0) lpart[blockIdx.x * 16 + blockIdx.y] = sm[0] + sm[1] + sm[2] + sm[3];
    // write phase: lanes = hw (coalesced)
    for (int i = 0; i < 64; ++i) {
        int idx = i * 256 + tid;
        int c = idx >> 6, hwl = idx & 63;
        zq_out[(size_t)b * ZSTRIDE + (size_t)c * HWN + hw0 + hwl] = zqt[hwl][c];
    }
}

__global__ void loss_final_kernel(const float* __restrict__ lpart, float* __restrict__ out) {
    __shared__ float sm[4];
    float s = 0.0f;
    for (int i = threadIdx.x; i < 128; i += 256) s += lpart[i];
    #pragma unroll
    for (int m = 32; m; m >>= 1) s += __shfl_xor(s, m, 64);
    if ((threadIdx.x & 63) == 0) sm[threadIdx.x >> 6] = s;
    __syncthreads();
    if (threadIdx.x == 0) {
        float total = sm[0] + sm[1] + sm[2] + sm[3];
        float m = total * (1.0f / 2097152.0f);
        out[0] = fmaf(0.25f, m, m);
    }
}

// ---------------- launch ----------------

extern "C" void kernel_launch(void* const* d_in, const int* in_sizes, int n_in,
                              void* d_out, int out_size, void* d_ws, size_t ws_size,
                              hipStream_t stream) {
    const float* z  = (const float*)d_in[0];
    const float* cb = (const float*)d_in[1];
    float* out = (float*)d_out;

    float* ws = (float*)d_ws;
    float*  cbrinv = ws;                                 // 16384
    float*  cbsq   = cbrinv + CN;                        // 16384
    int*    ridx   = (int*)(cbsq + CN);                  // 8192
    float*  lpart  = (float*)(ridx + ZM);                // 8192 (128 used)
    uint2*  part   = (uint2*)(lpart + ZM);               // 1 MB (16B-aligned)
    __bf16* Ah     = (__bf16*)(part + (size_t)ZM * NCHA);// 4 MB
    __bf16* Bh     = Ah + (size_t)ZM * KD;               // 8 MB
    float*  Zt     = (float*)(Bh + (size_t)CN * KD);     // 8 MB  (total ~21.4 MB)

    float* out_loss = out;
    float* out_zq   = out + 1;
    float* out_idx  = out + 1 + (size_t)ZM * KD;

    cbprep_kernel<<<CN, 256, 0, stream>>>(cb, cbrinv, cbsq, Bh);
    prep_a_kernel<<<dim3(16, 4, 8), 256, 0, stream>>>(z, Ah, Zt);
    gemm_top2_kernel<<<dim3(64, 16), 256, 0, stream>>>(Ah, Bh, part);
    rescue_all_kernel<<<ZM, 64, 0, stream>>>(Zt, cb, cbrinv, cbsq, part, ridx, out_idx);
    finalize_kernel<<<dim3(8, 16), 256, 0, stream>>>(Zt, cb, ridx, out_zq, lpart);
    loss_final_kernel<<<1, 256, 0, stream>>>(lpart, out_loss);
}

// Round 17
// 186.879 us; speedup vs baseline: 2.3557x; 1.0052x over previous
//
#include <hip/hip_runtime.h>
#include <float.h>
#include <math.h>

#define ZM 8192
#define CN 16384
#define KD 256
#define HWN 1024
#define ZSTRIDE 262144
#define NCHA 16     // 1024 codes per chunk, running top-2 per chunk

typedef short  s16x8  __attribute__((ext_vector_type(8)));
typedef float  f32x4  __attribute__((ext_vector_type(4)));

__device__ inline void gld_lds16(const void* g, void* l) {
    __builtin_amdgcn_global_load_lds((__attribute__((address_space(1))) void*)(g),
                                     (__attribute__((address_space(3))) void*)(l), 16, 0, 0);
}

// ---------------- fused cb stats + bf16 prep (one cb read) ----------------

__global__ void cbprep_kernel(const float* __restrict__ cb, float* __restrict__ cbrinv,
                              float* __restrict__ cbsq, __bf16* __restrict__ Bh) {
    __shared__ float sm[4];
    __shared__ float rsh;
    int n = blockIdx.x;
    float v = cb[(size_t)n * KD + threadIdx.x];
    float s = v * v;
    #pragma unroll
    for (int m = 32; m; m >>= 1) s += __shfl_xor(s, m, 64);
    if ((threadIdx.x & 63) == 0) sm[threadIdx.x >> 6] = s;
    __syncthreads();
    if (threadIdx.x == 0) {
        float t = sm[0] + sm[1] + sm[2] + sm[3];
        float r = 1.0f / fmaxf(sqrtf(t), 1e-12f);
        cbrinv[n] = r;
        cbsq[n] = t * r * r;
        rsh = r;
    }
    __syncthreads();
    Bh[(size_t)n * KD + threadIdx.x] = (__bf16)(v * rsh);
}

// ---------------- z transpose: bf16 Ah + f32 Zt ----------------

__global__ void prep_a_kernel(const float* __restrict__ z, __bf16* __restrict__ Ah,
                              float* __restrict__ Zt) {
    __shared__ float tile[64][65];
    int hw0 = blockIdx.x * 64, c0 = blockIdx.y * 64, b = blockIdx.z;
    int tid = threadIdx.x;
    #pragma unroll
    for (int i = 0; i < 16; ++i) {
        int lin = i * 256 + tid;
        int cl = lin >> 6, hwl = lin & 63;
        tile[cl][hwl] = z[(size_t)b * ZSTRIDE + (size_t)(c0 + cl) * HWN + hw0 + hwl];
    }
    __syncthreads();
    #pragma unroll
    for (int i = 0; i < 16; ++i) {
        int lin = i * 256 + tid;
        int hwl = lin >> 6, cl = lin & 63;
        float v = tile[cl][hwl];
        size_t o = (size_t)(b * 1024 + hw0 + hwl) * KD + c0 + cl;
        Ah[o] = (__bf16)v;
        Zt[o] = v;
    }
}

// ---------------- bf16 MFMA GEMM: BK=64, swizzled gld_lds, counted-vmcnt ----
// R16 base + (1) strength-reduced addressing: per-lane offsets precomputed,
// uniform pointer stepping, frag reads via base + imm offsets + element-XOR
// for the k-half; (2) T4 counted vmcnt: per step each wave waits only its own
// prior-step 8 loads (s_waitcnt vmcnt(8)), raw s_barrier joins all waves ->
// staged LDS globally consistent; no vmcnt(0) drain in the main loop.
// K accumulation order bit-identical to the R12/R16 pass.

__global__ __launch_bounds__(256, 2) void gemm_top2_kernel(
    const __bf16* __restrict__ A, const __bf16* __restrict__ B,
    uint2* __restrict__ part)
{
    __shared__ __bf16 sA[2][128 * 64];   // 16 KB per buf
    __shared__ __bf16 sB[2][128 * 64];
    __shared__ uint2 sred[2][128];

    const int tid = threadIdx.x;
    const int l = tid & 63;
    const int wid = tid >> 6;
    const int wm = (wid >> 1) * 64, wn = (wid & 1) * 64;
    const int m0 = blockIdx.x * 128;
    const int chunk = blockIdx.y;
    const int fr = l & 15;
    const int fkg = l >> 4;              // k-granule subindex 0..3

    // per-lane staging offsets (elements), computed once
    int laneOff[4], dstOff[4];
    #pragma unroll
    for (int j = 0; j < 4; ++j) {
        int sl = j * 256 + tid;          // 16B slot (wave-contiguous)
        int r = sl >> 3, c = sl & 7;
        int cs = c ^ (r & 7);            // inverse-swizzled global granule
        laneOff[j] = r * KD + cs * 8;
        dstOff[j] = sl * 8;
    }

    // frag base offsets (elements) within one 16KB buffer; kh flips elem bit 5
    const int cg0 = fkg ^ (fr & 7);
    const int fA0 = (wm + fr) * 64 + cg0 * 8;
    const int fB0 = (wn + fr) * 64 + cg0 * 8;

    unsigned khi[16], klo[16];
    #pragma unroll
    for (int sx = 0; sx < 16; ++sx) { khi[sx] = 0u; klo[sx] = 0u; }

    auto stage = [&](int buf, const __bf16* Ab, const __bf16* Bb) {
        #pragma unroll
        for (int j = 0; j < 4; ++j) {
            gld_lds16(Ab + laneOff[j], &sA[buf][dstOff[j]]);
            gld_lds16(Bb + laneOff[j], &sB[buf][dstOff[j]]);
        }
    };

    f32x4 acc[4][4];
    #pragma unroll
    for (int ti = 0; ti < 4; ++ti)
        #pragma unroll
        for (int tj = 0; tj < 4; ++tj) acc[ti][tj] = (f32x4){0.f, 0.f, 0.f, 0.f};

    const __bf16* Abase = A + (size_t)m0 * KD;
    const __bf16* Bbase = B + (size_t)chunk * 1024 * KD;

    stage(0, Abase, Bbase);              // step 0 (k0=0, t=0)
    const __bf16* An = Abase + 64;       // pointers for step 1
    const __bf16* Bn = Bbase + 64;

    int cur = 0;
    for (int s = 0; s < 32; ++s) {
        if (s + 1 < 32) {
            stage(cur ^ 1, An, Bn);      // next-step loads fly under compute
            if (((s + 1) & 3) == 3) { An -= 192; Bn += 128 * KD - 192; }
            else                    { An += 64;  Bn += 64; }
            asm volatile("s_waitcnt vmcnt(8)" ::: "memory");   // my prior 8 landed
        } else {
            asm volatile("s_waitcnt vmcnt(0)" ::: "memory");   // final drain
        }
        __builtin_amdgcn_s_barrier();    // all waves' waits done -> LDS consistent

        #pragma unroll
        for (int kh = 0; kh < 2; ++kh) {
            const __bf16* fB = &sB[cur][fB0 ^ (kh * 32)];
            const __bf16* fA = &sA[cur][fA0 ^ (kh * 32)];
            s16x8 bhf[4];
            #pragma unroll
            for (int tj = 0; tj < 4; ++tj)
                bhf[tj] = *(const s16x8*)(fB + tj * 1024);
            #pragma unroll
            for (int ti = 0; ti < 4; ++ti) {
                s16x8 ahf = *(const s16x8*)(fA + ti * 1024);
                #pragma unroll
                for (int tj = 0; tj < 4; ++tj)
                    acc[ti][tj] = __builtin_amdgcn_mfma_f32_16x16x32_bf16(ahf, bhf[tj], acc[ti][tj], 0, 0, 0);
            }
        }

        if ((s & 3) == 3) {
            const int t = s >> 2;
            // fold 4 candidates/row into packed running top-2, zero acc
            #pragma unroll
            for (int sx = 0; sx < 16; ++sx) {
                const int ti = sx >> 2, r = sx & 3;
                #pragma unroll
                for (int tj = 0; tj < 4; ++tj) {
                    unsigned u = __float_as_uint(acc[ti][tj][r]);
                    u ^= ((unsigned)((int)u >> 31)) | 0x80000000u;
                    unsigned key = (u & 0xFFFFFC00u) | (unsigned)(t * 128 + wn + tj * 16 + fr);
                    unsigned h = khi[sx];
                    unsigned mn = min(h, key);
                    khi[sx] = max(h, key);
                    klo[sx] = max(klo[sx], mn);
                    acc[ti][tj][r] = 0.f;
                }
            }
        }
        __builtin_amdgcn_s_barrier();    // reads of cur done before overwrite
        cur ^= 1;
    }

    // 16-lane butterfly merge, then cross-wave merge via LDS
    #pragma unroll
    for (int sx = 0; sx < 16; ++sx) {
        unsigned h = khi[sx], lo_ = klo[sx];
        #pragma unroll
        for (int m = 1; m < 16; m <<= 1) {
            unsigned oh = (unsigned)__shfl_xor((int)h, m, 64);
            unsigned ol = (unsigned)__shfl_xor((int)lo_, m, 64);
            unsigned nh = max(h, oh);
            lo_ = max(min(h, oh), max(lo_, ol));
            h = nh;
        }
        if ((l & 15) == 0) {
            int rowlb = wm + (sx >> 2) * 16 + (l >> 4) * 4 + (sx & 3);
            sred[wn >> 6][rowlb] = make_uint2(h, lo_);
        }
    }
    __syncthreads();
    if (tid < 128) {
        uint2 pa = sred[0][tid], pb = sred[1][tid];
        unsigned h = max(pa.x, pb.x);
        unsigned lo_ = max(min(pa.x, pb.x), max(pa.y, pb.y));
        part[(size_t)(m0 + tid) * NCHA + chunk] = make_uint2(h, lo_);
    }
}

// ---------------- exact fp32 rescue over all 32 candidates/row ----------------
// zrinv recomputed with a bit-identical replication of R1's reduction tree.

__global__ void rescue_all_kernel(const float* __restrict__ Zt, const float* __restrict__ cb,
                                  const float* __restrict__ cbrinv, const float* __restrict__ cbsq,
                                  const uint2* __restrict__ part,
                                  int* __restrict__ ridx, float* __restrict__ out_idx) {
    int row = blockIdx.x;
    __shared__ float zrow[KD];
    int tid = threadIdx.x;   // 64 threads; lanes 32..63 duplicate slots 0..31
    ((float4*)zrow)[tid] = ((const float4*)(Zt + (size_t)row * KD))[tid];
    __syncthreads();

    float tot = 0.f;
    #pragma unroll
    for (int w = 0; w < 4; ++w) {
        float v = zrow[w * 64 + tid];
        float s = v * v;
        #pragma unroll
        for (int m = 32; m; m >>= 1) s += __shfl_xor(s, m, 64);
        tot += s;
    }
    float zrinv = 1.0f / fmaxf(sqrtf(tot), 1e-12f);

    int slot = tid & 31;
    uint2 p = part[(size_t)row * NCHA + (slot >> 1)];
    unsigned key = (slot & 1) ? p.y : p.x;
    int n = (slot >> 1) * 1024 + (int)(key & 1023u);
    float sc = cbrinv[n];
    const float4* c4 = (const float4*)(cb + (size_t)n * KD);
    const float4* z4 = (const float4*)zrow;
    float acc = 0.f;
    #pragma unroll 8
    for (int k = 0; k < KD / 4; ++k) {
        float4 cv = c4[k];
        float4 zv = z4[k];
        acc = fmaf(zv.x, cv.x * sc, acc);
        acc = fmaf(zv.y, cv.y * sc, acc);
        acc = fmaf(zv.z, cv.z * sc, acc);
        acc = fmaf(zv.w, cv.w * sc, acc);
    }
    float s = fmaf(zrinv, acc, -0.5f * cbsq[n]);
    #pragma unroll
    for (int m = 1; m < 32; m <<= 1) {
        float ov = __shfl_xor(s, m, 64); int on = __shfl_xor(n, m, 64);
        if (ov > s || (ov == s && on < n)) { s = ov; n = on; }
    }
    if (tid == 0) { ridx[row] = n; out_idx[row] = (float)n; }
}

// ---------------- gather + z_q output (coalesced via LDS transpose) + loss ----------

__global__ void finalize_kernel(const float* __restrict__ Zt, const float* __restrict__ cb,
                                const int* __restrict__ ridx,
                                float* __restrict__ zq_out, float* __restrict__ lpart) {
    __shared__ float zqt[64][257];
    __shared__ int idxs[64];
    __shared__ float sm[4];
    int b = blockIdx.x, hw0 = blockIdx.y * 64, tid = threadIdx.x;
    if (tid < 64) idxs[tid] = ridx[b * 1024 + hw0 + tid];
    __syncthreads();
    float dsum = 0.f;
    for (int i = 0; i < 64; ++i) {                 // row i; lanes = channel c
        int row = b * 1024 + hw0 + i;
        float zt = Zt[(size_t)row * KD + tid];
        float zq = cb[(size_t)idxs[i] * KD + tid];
        float d = zq - zt;
        zqt[i][tid] = zt + d;                      // straight-through arithmetic
        dsum = fmaf(d, d, dsum);
    }
    #pragma unroll
    for (int m = 32; m; m >>= 1) dsum += __shfl_xor(dsum, m, 64);
    if ((tid & 63) == 0) sm[tid >> 6] = dsum;
    __syncthreads();
    if (tid == 0) lpart[blockIdx.x * 16 + blockIdx.y] = sm[0] + sm[1] + sm[2] + sm[3];
    // write phase: lanes = hw (coalesced)
    for (int i = 0; i < 64; ++i) {
        int idx = i * 256 + tid;
        int c = idx >> 6, hwl = idx & 63;
        zq_out[(size_t)b * ZSTRIDE + (size_t)c * HWN + hw0 + hwl] = zqt[hwl][c];
    }
}

__global__ void loss_final_kernel(const float* __restrict__ lpart, float* __restrict__ out) {
    __shared__ float sm[4];
    float s = 0.0f;
    for (int i = threadIdx.x; i < 128; i += 256) s += lpart[i];
    #pragma unroll
    for (int m = 32; m; m >>= 1) s += __shfl_xor(s, m, 64);
    if ((threadIdx.x & 63) == 0) sm[threadIdx.x >> 6] = s;
    __syncthreads();
    if (threadIdx.x == 0) {
        float total = sm[0] + sm[1] + sm[2] + sm[3];
        float m = total * (1.0f / 2097152.0f);
        out[0] = fmaf(0.25f, m, m);
    }
}

// ---------------- launch ----------------

extern "C" void kernel_launch(void* const* d_in, const int* in_sizes, int n_in,
                              void* d_out, int out_size, void* d_ws, size_t ws_size,
                              hipStream_t stream) {
    const float* z  = (const float*)d_in[0];
    const float* cb = (const float*)d_in[1];
    float* out = (float*)d_out;

    float* ws = (float*)d_ws;
    float*  cbrinv = ws;                                 // 16384
    float*  cbsq   = cbrinv + CN;                        // 16384
    int*    ridx   = (int*)(cbsq + CN);                  // 8192
    float*  lpart  = (float*)(ridx + ZM);                // 8192 (128 used)
    uint2*  part   = (uint2*)(lpart + ZM);               // 1 MB (16B-aligned)
    __bf16* Ah     = (__bf16*)(part + (size_t)ZM * NCHA);// 4 MB
    __bf16* Bh     = Ah + (size_t)ZM * KD;               // 8 MB
    float*  Zt     = (float*)(Bh + (size_t)CN * KD);     // 8 MB  (total ~21.4 MB)

    float* out_loss = out;
    float* out_zq   = out + 1;
    float* out_idx  = out + 1 + (size_t)ZM * KD;

    cbprep_kernel<<<CN, 256, 0, stream>>>(cb, cbrinv, cbsq, Bh);
    prep_a_kernel<<<dim3(16, 4, 8), 256, 0, stream>>>(z, Ah, Zt);
    gemm_top2_kernel<<<dim3(64, 16), 256, 0, stream>>>(Ah, Bh, part);
    rescue_all_kernel<<<ZM, 64, 0, stream>>>(Zt, cb, cbrinv, cbsq, part, ridx, out_idx);
    finalize_kernel<<<dim3(8, 16), 256, 0, stream>>>(Zt, cb, ridx, out_zq, lpart);
    loss_final_kernel<<<1, 256, 0, stream>>>(lpart, out_loss);
}